// Round 12
// baseline (122.007 us; speedup 1.0000x reference)
//
#include <hip/hip_runtime.h>
#include <hip/hip_bf16.h>
#include <math.h>

#define LL 96
#define LP 768
#define BD 256
#define HD 128
#define NB 2
#define NEGV (-20.0f)
#define LB 8    // ligands per block
#define PB 16   // proteins per block

#define NBIN 4096    // top-12-bit key histogram
#define BSHIFT 20
#define CAP 8192     // candidate buffer per batch
#define NLOG (LL * LP)

typedef __attribute__((ext_vector_type(4))) float f32x4;
typedef __attribute__((ext_vector_type(4))) unsigned int u32x4;
typedef __attribute__((ext_vector_type(8))) short s16x8;

// Abramowitz-Stegun 7.1.26 erf, |err| <= 1.5e-7 absolute.
__device__ __forceinline__ float gelu_fast(float x) {
  float ax = fabsf(x) * 0.70710678118654752f;
  float t = __builtin_amdgcn_rcpf(fmaf(0.3275911f, ax, 1.0f));
  float poly = t * fmaf(t, fmaf(t, fmaf(t, fmaf(t, 1.061405429f, -1.453152027f),
                                        1.421413741f), -0.284496736f), 0.254829592f);
  float e = __expf(-ax * ax);
  float erfax = fmaf(-poly, e, 1.0f);
  float erfx = copysignf(erfax, x);
  return 0.5f * x * (1.0f + erfx);
}

__device__ __forceinline__ f32x4 mfma16(s16x8 a, s16x8 b, f32x4 c) {
  return __builtin_amdgcn_mfma_f32_16x16x32_bf16(a, b, c, 0, 0, 0);
}

__device__ __forceinline__ unsigned pack_bf16(float a, float b) {
  float2 t; t.x = a; t.y = b;
  __hip_bfloat162 h = __float22bfloat162_rn(t);
  return *reinterpret_cast<unsigned*>(&h);
}

__device__ __forceinline__ s16x8 as_s16x8(u32x4 v) {
  return __builtin_bit_cast(s16x8, v);
}

// 8 f32 -> s16x8 bf16 fragment (j order preserved)
__device__ __forceinline__ s16x8 pack8(f32x4 x0, f32x4 x1) {
  u32x4 v;
  v[0] = pack_bf16(x0[0], x0[1]);
  v[1] = pack_bf16(x0[2], x0[3]);
  v[2] = pack_bf16(x1[0], x1[1]);
  v[3] = pack_bf16(x1[2], x1[3]);
  return as_s16x8(v);
}

__device__ __forceinline__ unsigned short bfbits(float x) {
  __hip_bfloat16 h = __float2bfloat16(x);
  return *reinterpret_cast<unsigned short*>(&h);
}

__device__ __forceinline__ unsigned int fkey(float f) {
  unsigned int u = __float_as_uint(f);
  return u ^ ((u >> 31) ? 0xFFFFFFFFu : 0x80000000u);
}
__device__ __forceinline__ float finv(unsigned int k) {
  unsigned int u = k ^ ((k >> 31) ? 0x80000000u : 0xFFFFFFFFu);
  return __uint_as_float(u);
}

// ctrl layout (u32): [0,1]=ubkey (>= max)  [2,3]=binB count  [4,5]=B  [6,7]=G
//   [8,9]=s1(float) [10,11]=s2(float) [12,13]=hist ticket [14,15]=sums ticket
//   [16,17]=findbin-done flag  [18..31]=pad

// ---- launch 1: pad decode + zero | ALL weight swizzles into frag order -----
// Segments (elem idx): [0,65536) W1xf | [65536,81920) W2f | [81920,147456) Wlf
// | [147456,212992) Wpf | [212992,278528) W1abf (part0=rows 0:256 for ligand,
// part1=rows 256:512 for protein).
__global__ __launch_bounds__(256) void swz_kernel(
    const void* lp, const void* pp, unsigned char* lmask, unsigned char* pmask,
    const float* __restrict__ W1, const float* __restrict__ W2,
    const float* __restrict__ Wl, const float* __restrict__ Wp,
    unsigned short* __restrict__ W1xf, unsigned short* __restrict__ W2f,
    unsigned short* __restrict__ Wlf, unsigned short* __restrict__ Wpf,
    unsigned short* __restrict__ W1abf, unsigned* __restrict__ zero_base) {
  __shared__ int bad;
  const int tid = threadIdx.x;
  if (blockIdx.x == 0) {
    for (int i = tid; i < NB * NBIN + 32; i += 256) zero_base[i] = 0u;
    if (tid == 0) bad = 0;
    __syncthreads();
    const unsigned int* li = (const unsigned int*)lp;
    const unsigned int* pi = (const unsigned int*)pp;
    for (int i = tid; i < NB * LL; i += 256) if (li[i] > 1u) atomicOr(&bad, 1);
    for (int i = tid; i < NB * LP; i += 256) if (pi[i] > 1u) atomicOr(&bad, 1);
    __syncthreads();
    const bool asInt = (bad == 0);
    const unsigned char* lb = (const unsigned char*)lp;
    const unsigned char* pb = (const unsigned char*)pp;
    for (int i = tid; i < NB * LL; i += 256)
      lmask[i] = asInt ? (unsigned char)(li[i] != 0u) : (unsigned char)(lb[i] != 0);
    for (int i = tid; i < NB * LP; i += 256)
      pmask[i] = asInt ? (unsigned char)(pi[i] != 0u) : (unsigned char)(pb[i] != 0);
    return;
  }
  int idx = (blockIdx.x - 1) * 256 + tid;
  if (idx < 65536) {
    int j = idx & 7, ln = (idx >> 3) & 63;
    int rest = idx >> 9;
    int mt = rest & 7, kt = (rest >> 3) & 1, cc = rest >> 4;
    int row = 512 + cc * 64 + kt * 32 + ((ln >> 4) << 3) + j;
    int col = mt * 16 + (ln & 15);
    W1xf[idx] = bfbits(W1[row * HD + col]);
  } else if (idx < 81920) {
    int e = idx - 65536;
    int j = e & 7, ln = (e >> 3) & 63, mt = (e >> 9) & 7, kt = e >> 12;
    int row = kt * 32 + ((ln >> 4) << 3) + j;
    int col = mt * 16 + (ln & 15);
    W2f[e] = bfbits(W2[row * HD + col]);
  } else if (idx < 147456) {
    int e = idx - 81920;  // [kt8][nt16][lane64][j8]
    int j = e & 7, ln = (e >> 3) & 63, nt = (e >> 9) & 15, kt = e >> 13;
    int row = kt * 32 + ((ln >> 4) << 3) + j;
    int col = nt * 16 + (ln & 15);
    Wlf[e] = bfbits(Wl[row * 256 + col]);
  } else if (idx < 212992) {
    int e = idx - 147456;
    int j = e & 7, ln = (e >> 3) & 63, nt = (e >> 9) & 15, kt = e >> 13;
    int row = kt * 32 + ((ln >> 4) << 3) + j;
    int col = nt * 16 + (ln & 15);
    Wpf[e] = bfbits(Wp[row * 256 + col]);
  } else if (idx < 278528) {
    int e = idx - 212992;  // [part2][kt8][nt8][lane64][j8]
    int j = e & 7, ln = (e >> 3) & 63, nt = (e >> 9) & 7, kt = (e >> 12) & 7;
    int part = e >> 15;
    int row = part * 256 + kt * 32 + ((ln >> 4) << 3) + j;
    int col = nt * 16 + (ln & 15);
    W1abf[e] = bfbits(W1[row * HD + col]);
  }
}

// ---- launch 2: MFMA projection chain from pre-swizzled frags ----------------
// Y1 = X@W+b (256 cols); Y2 = Y1@W1part(+b1) (128 cols). One 16B frag load
// per (kt,nt) instead of 8 stride-1KB scalar loads.
__global__ __launch_bounds__(256) void proj_kernel(
    const float* __restrict__ l_tok, const float* __restrict__ p_tok,
    const unsigned short* __restrict__ Wlf, const unsigned short* __restrict__ Wpf,
    const unsigned short* __restrict__ W1abf,
    const float* __restrict__ bl, const float* __restrict__ bp,
    const float* __restrict__ b1,
    float* __restrict__ wl_, float* __restrict__ wp_,
    float* __restrict__ wA, float* __restrict__ wB) {
  const int tid = threadIdx.x;
  const bool isL = blockIdx.x < (NB * LL / 16);
  const int blk = isL ? blockIdx.x : (blockIdx.x - NB * LL / 16);
  const int r0 = blk * 16;
  const float* X = isL ? l_tok : p_tok;
  const unsigned short* Wf = isL ? Wlf : Wpf;
  const float* bias = isL ? bl : bp;
  float* Y1 = isL ? wl_ : wp_;
  float* Y2 = isL ? wA : wB;
  const unsigned short* Wab = W1abf + (isL ? 0 : 32768);

  const int lane = tid & 63;
  const int wv = tid >> 6;
  const int mrow = lane & 15;
  const int kg = (lane >> 4) * 8;
  const int drow = (lane >> 4) * 4;

  // phase A: 256 cols, wave wv owns nt = wv*4+q
  f32x4 accA[4];
#pragma unroll
  for (int q = 0; q < 4; ++q) {
    float bv = bias[(wv * 4 + q) * 16 + mrow];
    accA[q] = (f32x4){bv, bv, bv, bv};
  }
#pragma unroll
  for (int kt = 0; kt < 8; ++kt) {
    const float* xr = &X[(size_t)(r0 + mrow) * 256 + kt * 32 + kg];
    s16x8 af = pack8(*(const f32x4*)xr, *(const f32x4*)(xr + 4));
#pragma unroll
    for (int q = 0; q < 4; ++q) {
      const int nt = wv * 4 + q;
      s16x8 bf = *(const s16x8*)(Wf + ((size_t)((kt * 16 + nt) * 64 + lane)) * 8);
      accA[q] = mfma16(af, bf, accA[q]);
    }
  }
#pragma unroll
  for (int q = 0; q < 4; ++q)
#pragma unroll
    for (int r = 0; r < 4; ++r)
      Y1[(size_t)(r0 + drow + r) * 256 + (wv * 4 + q) * 16 + mrow] = accA[q][r];
  __syncthreads();  // Y1 stores drained before cross-wave re-read

  // phase B: 128 cols, wave wv owns nt = wv*2+q
  f32x4 accB[2];
#pragma unroll
  for (int q = 0; q < 2; ++q) {
    float bv = isL ? b1[(wv * 2 + q) * 16 + mrow] : 0.0f;
    accB[q] = (f32x4){bv, bv, bv, bv};
  }
#pragma unroll
  for (int kt = 0; kt < 8; ++kt) {
    const float* yr = &Y1[(size_t)(r0 + mrow) * 256 + kt * 32 + kg];
    s16x8 af = pack8(*(const f32x4*)yr, *(const f32x4*)(yr + 4));
#pragma unroll
    for (int q = 0; q < 2; ++q) {
      const int nt = wv * 2 + q;
      s16x8 bf = *(const s16x8*)(Wab + ((size_t)((kt * 8 + nt) * 64 + lane)) * 8);
      accB[q] = mfma16(af, bf, accB[q]);
    }
  }
#pragma unroll
  for (int q = 0; q < 2; ++q)
#pragma unroll
    for (int r = 0; r < 4; ++r)
      Y2[(size_t)(r0 + drow + r) * HD + (wv * 2 + q) * 16 + mrow] = accB[q][r];
}

// ---- MFMA pair kernel: 8m x 2n, rcp-gelu, 3 blocks/CU (validated round 11) --
__global__ __launch_bounds__(256, 3) void pair2_kernel(
    const float* __restrict__ lbuf, const float* __restrict__ pbuf,
    const float* __restrict__ A1, const float* __restrict__ B1,
    const unsigned short* __restrict__ W1xf, const unsigned short* __restrict__ W2f,
    const float* __restrict__ b2, const float* __restrict__ W3,
    const float* __restrict__ b3, const unsigned char* __restrict__ lmask,
    const unsigned char* __restrict__ pmask, float* __restrict__ logits) {
  __shared__ float U[8192];

  const int tid = threadIdx.x;
  const int lane = tid & 63;
  const int w = tid >> 6;
  const int g = lane >> 4;
  const int c = lane & 15;
  const int bb = blockIdx.z;
  const int i0 = blockIdx.y * LB;
  const int j0 = blockIdx.x * PB;

  float* lt0 = U;
  float* lt1 = U + 1632;

  const int srow = tid >> 4, sq = tid & 15;
  const int srow2 = (tid + 256) >> 4;

  auto gaddr = [&](int row, int q, int c4) -> const float* {
    return (row < 8)
        ? &lbuf[(size_t)(bb * LL + i0 + row) * BD + c4 * 64 + q * 4]
        : &pbuf[(size_t)(bb * LP + j0 + (row - 8)) * BD + c4 * 64 + q * 4];
  };

  {
    f32x4 r0 = *(const f32x4*)gaddr(srow, sq, 0);
    f32x4 r1 = {};
    if (tid < 128) r1 = *(const f32x4*)gaddr(srow2, sq, 0);
    *(f32x4*)&lt0[srow * 68 + sq * 4] = r0;
    if (tid < 128) *(f32x4*)&lt0[srow2 * 68 + sq * 4] = r1;
  }
  __syncthreads();

  f32x4 acc1[8][2];
#pragma unroll
  for (int m = 0; m < 8; ++m)
#pragma unroll
    for (int n = 0; n < 2; ++n) acc1[m][n] = (f32x4)0.0f;

  for (int c4 = 0; c4 < 4; ++c4) {
    float* cur = (c4 & 1) ? lt1 : lt0;
    float* nxt = (c4 & 1) ? lt0 : lt1;

    f32x4 r0 = {}, r1 = {};
    if (c4 < 3) {
      r0 = *(const f32x4*)gaddr(srow, sq, c4 + 1);
      if (tid < 128) r1 = *(const f32x4*)gaddr(srow2, sq, c4 + 1);
    }

#pragma unroll
    for (int kt = 0; kt < 2; ++kt) {
      const int kc0 = kt * 32 + g * 8;
      // A-frag batch 0 in flight...
      s16x8 a0[8];
#pragma unroll
      for (int m = 0; m < 8; ++m)
        a0[m] = *(const s16x8*)(W1xf +
            ((size_t)((c4 * 2 + kt) * 8 + m) * 64 + lane) * 8);

      // ...covered by bf0 build
      const f32x4 p0 = *(const f32x4*)&cur[(8 + c) * 68 + kc0];
      const f32x4 p1 = *(const f32x4*)&cur[(8 + c) * 68 + kc0 + 4];
      s16x8 bf0[2], bf1[2];
#pragma unroll
      for (int n = 0; n < 2; ++n) {
        const int ntg = w * 2 + n;
        const f32x4 l0 = *(const f32x4*)&cur[ntg * 68 + kc0];
        const f32x4 l1 = *(const f32x4*)&cur[ntg * 68 + kc0 + 4];
        u32x4 bv;
        bv[0] = pack_bf16(l0[0] * p0[0], l0[1] * p0[1]);
        bv[1] = pack_bf16(l0[2] * p0[2], l0[3] * p0[3]);
        bv[2] = pack_bf16(l1[0] * p1[0], l1[1] * p1[1]);
        bv[3] = pack_bf16(l1[2] * p1[2], l1[3] * p1[3]);
        bf0[n] = as_s16x8(bv);
      }

      // A-frag batch 1 in flight...
      s16x8 a1[8];
#pragma unroll
      for (int m = 0; m < 8; ++m)
        a1[m] = *(const s16x8*)(W1xf +
            ((size_t)(((4 + c4) * 2 + kt) * 8 + m) * 64 + lane) * 8);

      // ...covered by bf1 build
#pragma unroll
      for (int n = 0; n < 2; ++n) {
        const int ntg = w * 2 + n;
        const f32x4 l0 = *(const f32x4*)&cur[ntg * 68 + kc0];
        const f32x4 l1 = *(const f32x4*)&cur[ntg * 68 + kc0 + 4];
        u32x4 bv;
        bv[0] = pack_bf16(fabsf(l0[0] - p0[0]), fabsf(l0[1] - p0[1]));
        bv[1] = pack_bf16(fabsf(l0[2] - p0[2]), fabsf(l0[3] - p0[3]));
        bv[2] = pack_bf16(fabsf(l1[0] - p1[0]), fabsf(l1[1] - p1[1]));
        bv[3] = pack_bf16(fabsf(l1[2] - p1[2]), fabsf(l1[3] - p1[3]));
        bf1[n] = as_s16x8(bv);
      }

#pragma unroll
      for (int m = 0; m < 8; ++m) {
        acc1[m][0] = mfma16(a0[m], bf0[0], acc1[m][0]);
        acc1[m][1] = mfma16(a0[m], bf0[1], acc1[m][1]);
      }
#pragma unroll
      for (int m = 0; m < 8; ++m) {
        acc1[m][0] = mfma16(a1[m], bf1[0], acc1[m][0]);
        acc1[m][1] = mfma16(a1[m], bf1[1], acc1[m][1]);
      }
    }

    if (c4 < 3) {
      *(f32x4*)&nxt[srow * 68 + sq * 4] = r0;
      if (tid < 128) *(f32x4*)&nxt[srow2 * 68 + sq * 4] = r1;
    }
    __syncthreads();
  }

  unsigned* Hdw = (unsigned*)U;
#pragma unroll
  for (int m = 0; m < 8; ++m) {
    const int kt2 = (4 * m + g) >> 3;
    const int l2 = ((2 * m + (g >> 1)) & 3) * 16 + c;
    const int jd = (g & 1) * 2;
    const f32x4 b1v = *(const f32x4*)&B1[(size_t)(bb * LP + j0 + c) * HD + m * 16 + g * 4];
#pragma unroll
    for (int n = 0; n < 2; ++n) {
      const int ntg = w * 2 + n;
      f32x4 a1v = *(const f32x4*)&A1[(size_t)(bb * LL + i0 + ntg) * HD + m * 16 + g * 4];
      float h0 = gelu_fast(acc1[m][n][0] + a1v[0] + b1v[0]);
      float h1 = gelu_fast(acc1[m][n][1] + a1v[1] + b1v[1]);
      float h2 = gelu_fast(acc1[m][n][2] + a1v[2] + b1v[2]);
      float h3 = gelu_fast(acc1[m][n][3] + a1v[3] + b1v[3]);
      uint2 hw;
      hw.x = pack_bf16(h0, h1);
      hw.y = pack_bf16(h2, h3);
      *(uint2*)&Hdw[((kt2 * 8 + ntg) * 64 + l2) * 4 + jd] = hw;
    }
  }
  __syncthreads();

  f32x4 acc2[8][2];
#pragma unroll
  for (int m = 0; m < 8; ++m)
#pragma unroll
    for (int n = 0; n < 2; ++n) acc2[m][n] = (f32x4)0.0f;

  const unsigned short* Hush = (const unsigned short*)U;
#pragma unroll
  for (int kt = 0; kt < 4; ++kt) {
    s16x8 a2[8];
#pragma unroll
    for (int m = 0; m < 8; ++m)
      a2[m] = *(const s16x8*)(W2f + (size_t)((kt * 8 + m) * 64 + lane) * 8);
    s16x8 bf[2];
#pragma unroll
    for (int n = 0; n < 2; ++n)
      bf[n] = *((const s16x8*)Hush + ((kt * 8 + (w * 2 + n)) * 64 + lane));
#pragma unroll
    for (int m = 0; m < 8; ++m) {
      acc2[m][0] = mfma16(a2[m], bf[0], acc2[m][0]);
      acc2[m][1] = mfma16(a2[m], bf[1], acc2[m][1]);
    }
  }

  float partial[2] = {0.0f, 0.0f};
#pragma unroll
  for (int m = 0; m < 8; ++m) {
    const int hb = m * 16 + g * 4;
    f32x4 b2v = *(const f32x4*)&b2[hb];
    f32x4 w3v = *(const f32x4*)&W3[hb];
#pragma unroll
    for (int n = 0; n < 2; ++n) {
#pragma unroll
      for (int r = 0; r < 4; ++r)
        partial[n] = fmaf(gelu_fast(acc2[m][n][r] + b2v[r]), w3v[r], partial[n]);
    }
  }
#pragma unroll
  for (int n = 0; n < 2; ++n) {
    partial[n] += __shfl_xor(partial[n], 16, 64);
    partial[n] += __shfl_xor(partial[n], 32, 64);
  }
  if (g == 0) {
    const float bb3 = b3[0];
#pragma unroll
    for (int n = 0; n < 2; ++n) {
      const int ntg = w * 2 + n;
      float v = partial[n] + bb3;
      if (isnan(v)) v = 0.0f;
      else if (isinf(v)) v = (v > 0.0f) ? 20.0f : NEGV;
      const int i = i0 + ntg, j = j0 + c;
      if (lmask[bb * LL + i] || pmask[bb * LP + j]) v = NEGV;
      logits[(size_t)bb * NLOG + i * LP + j] = v;
    }
  }
}

// ----- merged top-k: hist -> (last block) findbin -> flag -> sums -> final --
__global__ __launch_bounds__(256) void topk_kernel(const float* __restrict__ logits,
                                                   unsigned* __restrict__ hist,
                                                   unsigned* __restrict__ ctrl,
                                                   float* __restrict__ cand,
                                                   float* __restrict__ out) {
  __shared__ unsigned lh[NBIN];
  __shared__ unsigned csum[256];
  __shared__ unsigned suf[256];
  __shared__ unsigned topb[256];
  __shared__ float red[256];
  __shared__ unsigned sP, sN, isLastS;
  __shared__ unsigned bc[8];
  const int b = blockIdx.y;
  const int tid = threadIdx.x;
  const float* data = logits + (size_t)b * NLOG;
  const int stride = gridDim.x * 256;

  // ---- phase 1: histogram ----
  for (int i = tid; i < NBIN; i += 256) lh[i] = 0u;
  __syncthreads();
  for (int i = blockIdx.x * 256 + tid; i < NLOG; i += stride)
    atomicAdd(&lh[fkey(data[i]) >> BSHIFT], 1u);
  __syncthreads();
  unsigned* gh = hist + b * NBIN;
  for (int i = tid; i < NBIN; i += 256) {
    unsigned v = lh[i];
    if (v) atomicAdd(&gh[i], v);
  }
  __threadfence();
  if (tid == 0) isLastS = (atomicAdd(&ctrl[12 + b], 1u) == gridDim.x - 1);
  __syncthreads();

  if (isLastS) {
    __threadfence();  // acquire: all blocks' gh updates visible
    const int base = tid * (NBIN / 256);
    unsigned s = 0;
    int top = -1;
    for (int i = 0; i < NBIN / 256; ++i) {
      unsigned cnt = gh[base + i];
      s += cnt;
      if (cnt) top = base + i;
    }
    csum[tid] = s;
    topb[tid] = (unsigned)(top + 1);
    __syncthreads();
    if (tid == 0) {
      unsigned a = 0;
      for (int t = 255; t >= 0; --t) { suf[t] = a; a += csum[t]; }
      unsigned mt = 0;
      for (int t = 0; t < 256; ++t) mt = max(mt, topb[t]);
      ctrl[b] = ((mt - 1u) << BSHIFT) | ((1u << BSHIFT) - 1u);  // ub >= max
    }
    __syncthreads();
    unsigned above = suf[tid];
    if (above < 100u && above + csum[tid] >= 100u) {
      unsigned a = above;
      for (int i = NBIN / 256 - 1; i >= 0; --i) {
        unsigned hc = gh[base + i];
        if (a + hc >= 100u) { ctrl[4 + b] = base + i; ctrl[6 + b] = a; break; }
        a += hc;
      }
    }
    __syncthreads();
    __threadfence();  // release B/G/ub before flag
    if (tid == 0) atomicExch(&ctrl[16 + b], 1u);
  } else {
    if (tid == 0) {
      int guard = 0;
      while (atomicAdd(&ctrl[16 + b], 0u) == 0u && guard < (1 << 24)) {
        __builtin_amdgcn_s_sleep(32);
        ++guard;
      }
    }
    __syncthreads();
  }

  // broadcast findbin results (atomic reads bypass stale L1)
  if (tid == 0) {
    bc[0] = atomicAdd(&ctrl[4 + b], 0u);   // B
    bc[1] = atomicAdd(&ctrl[b], 0u);       // ubkey
  }
  __syncthreads();
  const unsigned B = bc[0];
  const float vmax = finv(bc[1]);

  // ---- phase 2: sums above bin B + collect bin-B candidates ----
  {
    float l1 = 0.0f, l2 = 0.0f;
    for (int i = blockIdx.x * 256 + tid; i < NLOG; i += stride) {
      float v = data[i];
      unsigned kb = fkey(v) >> BSHIFT;
      if (kb > B) {
        float e = __expf(v - vmax);
        l1 += e;
        l2 = fmaf(e, v, l2);
      } else if (kb == B) {
        unsigned pos = atomicAdd(&ctrl[2 + b], 1u);
        if (pos < CAP) cand[(size_t)b * CAP + pos] = v;
      }
    }
    if (l1 != 0.0f) {
      atomicAdd((float*)&ctrl[8 + b], l1);
      atomicAdd((float*)&ctrl[10 + b], l2);
    }
  }
  __threadfence();
  if (tid == 0) isLastS = (atomicAdd(&ctrl[14 + b], 1u) == gridDim.x - 1);
  __syncthreads();
  if (!isLastS) return;
  __threadfence();  // acquire: cand + partial sums visible

  // ---- final: exact select among candidates + combine ----
  if (tid == 0) {
    bc[2] = atomicAdd(&ctrl[2 + b], 0u);
    bc[3] = atomicAdd(&ctrl[6 + b], 0u);
    bc[4] = __float_as_uint(atomicAdd((float*)&ctrl[8 + b], 0.0f));
    bc[5] = __float_as_uint(atomicAdd((float*)&ctrl[10 + b], 0.0f));
  }
  __syncthreads();
  const unsigned count = bc[2];
  const unsigned G = bc[3];
  const float s1g = __uint_as_float(bc[4]);
  const float s2g = __uint_as_float(bc[5]);
  const float* cv = cand + (size_t)b * CAP;
  const bool fb = count > CAP;  // degenerate fallback: full-array select
  const unsigned C = fb ? 0u : count;

  if (tid == 0) { sP = 0u; sN = fb ? 100u : (100u - G); }
  __syncthreads();

  for (int sh = 24; sh >= 0; sh -= 8) {
    csum[tid] = 0u;
    __syncthreads();
    const unsigned prefix = sP;
    const unsigned maskhi = (sh == 24) ? 0u : (0xFFFFFFFFu << (sh + 8));
    if (!fb) {
      for (int i = tid; i < (int)C; i += 256) {
        unsigned k = fkey(cv[i]);
        if ((k & maskhi) == (prefix & maskhi)) atomicAdd(&csum[(k >> sh) & 255], 1u);
      }
    } else {
      for (int i = tid; i < NLOG; i += 256) {
        unsigned k = fkey(data[i]);
        if ((k & maskhi) == (prefix & maskhi)) atomicAdd(&csum[(k >> sh) & 255], 1u);
      }
    }
    __syncthreads();
    if (tid == 0) {
      unsigned need = sN, cum = 0u;
      int d = 0;
      for (d = 255; d >= 0; --d) { cum += csum[d]; if (cum >= need) break; }
      sN = need - (cum - csum[d]);
      sP = prefix | ((unsigned)d << sh);
    }
    __syncthreads();
  }
  const unsigned Tkey = sP;
  const unsigned nT = sN;
  const float T = finv(Tkey);

  float l1 = 0.0f, l2 = 0.0f;
  if (!fb) {
    for (int i = tid; i < (int)C; i += 256) {
      float v = cv[i];
      if (fkey(v) > Tkey) { float e = __expf(v - vmax); l1 += e; l2 = fmaf(e, v, l2); }
    }
  } else {
    for (int i = tid; i < NLOG; i += 256) {
      float v = data[i];
      if (fkey(v) > Tkey) { float e = __expf(v - vmax); l1 += e; l2 = fmaf(e, v, l2); }
    }
  }
  red[tid] = l1;
  __syncthreads();
  for (int s = 128; s > 0; s >>= 1) { if (tid < s) red[tid] += red[tid + s]; __syncthreads(); }
  const float s1c = red[0];
  __syncthreads();
  red[tid] = l2;
  __syncthreads();
  for (int s = 128; s > 0; s >>= 1) { if (tid < s) red[tid] += red[tid + s]; __syncthreads(); }
  if (tid == 0) {
    const float s2c = red[0];
    const float e = __expf(T - vmax);
    const float g1 = fb ? 0.0f : s1g;
    const float g2 = fb ? 0.0f : s2g;
    const float denom = g1 + s1c + (float)nT * e;
    const float num = g2 + s2c + (float)nT * e * T;
    out[b] = num / denom;
  }
}

// ---------------------------------------------------------------------------
extern "C" void kernel_launch(void* const* d_in, const int* in_sizes, int n_in,
                              void* d_out, int out_size, void* d_ws, size_t ws_size,
                              hipStream_t stream) {
  const float* l_tok = (const float*)d_in[0];
  const float* p_tok = (const float*)d_in[1];
  const void* l_pad = d_in[2];
  const void* p_pad = d_in[3];
  const float* Wl = (const float*)d_in[4];
  const float* bl = (const float*)d_in[5];
  const float* Wp = (const float*)d_in[6];
  const float* bp = (const float*)d_in[7];
  const float* W1 = (const float*)d_in[8];
  const float* b1 = (const float*)d_in[9];
  const float* W2 = (const float*)d_in[10];
  const float* b2 = (const float*)d_in[11];
  const float* W3 = (const float*)d_in[12];
  const float* b3 = (const float*)d_in[13];

  float* ws = (float*)d_ws;
  float* wl_ = ws;                    // Y1 ligand [2,96,256]
  float* wp_ = ws + 49152;            // Y1 protein [2,768,256]
  float* wA = ws + 442368;            // A1 [2,96,128]
  float* wB = ws + 466944;            // B1 [2,768,128]
  float* wLog = ws + 663552;          // logits [2,73728]
  unsigned char* lmask = (unsigned char*)(ws + 811008);
  unsigned char* pmask = lmask + NB * LL;
  unsigned short* W1xf = (unsigned short*)(ws + 811520);  // 65536 u16
  unsigned short* W2f = (unsigned short*)(ws + 844288);   // 16384 u16
  unsigned* hist = (unsigned*)(ws + 852480);              // [2][NBIN] u32
  unsigned* ctrl = (unsigned*)(ws + 852480 + NB * NBIN);  // 32 u32
  float* cand = ws + 852480 + NB * NBIN + 32;             // [2][CAP]
  unsigned short* Wlf = (unsigned short*)(ws + 877088);   // 65536 u16
  unsigned short* Wpf = (unsigned short*)(ws + 909856);   // 65536 u16
  unsigned short* W1abf = (unsigned short*)(ws + 942624); // 65536 u16

  swz_kernel<<<1 + 278528 / 256, 256, 0, stream>>>(
      l_pad, p_pad, lmask, pmask, W1, W2, Wl, Wp,
      W1xf, W2f, Wlf, Wpf, W1abf, hist);

  proj_kernel<<<NB * (LL + LP) / 16, 256, 0, stream>>>(
      l_tok, p_tok, Wlf, Wpf, W1abf, bl, bp, b1, wl_, wp_, wA, wB);

  dim3 grid(LP / PB, LL / LB, NB);
  pair2_kernel<<<grid, 256, 0, stream>>>(wl_, wp_, wA, wB, W1xf, W2f,
                                         b2, W3, b3, lmask, pmask, wLog);
  topk_kernel<<<dim3(32, NB), 256, 0, stream>>>(wLog, hist, ctrl, cand,
                                                (float*)d_out);
}

// Round 13
// 114.712 us; speedup vs baseline: 1.0636x; 1.0636x over previous
//
#include <hip/hip_runtime.h>
#include <hip/hip_bf16.h>
#include <math.h>

#define LL 96
#define LP 768
#define BD 256
#define HD 128
#define NB 2
#define NEGV (-20.0f)
#define LB 8    // ligands per block
#define PB 16   // proteins per block

#define NBIN 4096    // top-12-bit key histogram
#define BSHIFT 20
#define CAP 8192     // candidate buffer per batch
#define NLOG (LL * LP)

typedef __attribute__((ext_vector_type(4))) float f32x4;
typedef __attribute__((ext_vector_type(4))) unsigned int u32x4;
typedef __attribute__((ext_vector_type(8))) short s16x8;

// Abramowitz-Stegun 7.1.26 erf, |err| <= 1.5e-7 absolute.
__device__ __forceinline__ float gelu_fast(float x) {
  float ax = fabsf(x) * 0.70710678118654752f;
  float t = __builtin_amdgcn_rcpf(fmaf(0.3275911f, ax, 1.0f));
  float poly = t * fmaf(t, fmaf(t, fmaf(t, fmaf(t, 1.061405429f, -1.453152027f),
                                        1.421413741f), -0.284496736f), 0.254829592f);
  float e = __expf(-ax * ax);
  float erfax = fmaf(-poly, e, 1.0f);
  float erfx = copysignf(erfax, x);
  return 0.5f * x * (1.0f + erfx);
}

__device__ __forceinline__ f32x4 mfma16(s16x8 a, s16x8 b, f32x4 c) {
  return __builtin_amdgcn_mfma_f32_16x16x32_bf16(a, b, c, 0, 0, 0);
}

__device__ __forceinline__ unsigned pack_bf16(float a, float b) {
  float2 t; t.x = a; t.y = b;
  __hip_bfloat162 h = __float22bfloat162_rn(t);
  return *reinterpret_cast<unsigned*>(&h);
}

__device__ __forceinline__ s16x8 as_s16x8(u32x4 v) {
  return __builtin_bit_cast(s16x8, v);
}

// 8 f32 -> s16x8 bf16 fragment (j order preserved)
__device__ __forceinline__ s16x8 pack8(f32x4 x0, f32x4 x1) {
  u32x4 v;
  v[0] = pack_bf16(x0[0], x0[1]);
  v[1] = pack_bf16(x0[2], x0[3]);
  v[2] = pack_bf16(x1[0], x1[1]);
  v[3] = pack_bf16(x1[2], x1[3]);
  return as_s16x8(v);
}

__device__ __forceinline__ unsigned short bfbits(float x) {
  __hip_bfloat16 h = __float2bfloat16(x);
  return *reinterpret_cast<unsigned short*>(&h);
}

__device__ __forceinline__ unsigned int fkey(float f) {
  unsigned int u = __float_as_uint(f);
  return u ^ ((u >> 31) ? 0xFFFFFFFFu : 0x80000000u);
}
__device__ __forceinline__ float finv(unsigned int k) {
  unsigned int u = k ^ ((k >> 31) ? 0x80000000u : 0xFFFFFFFFu);
  return __uint_as_float(u);
}

// ctrl layout (u32): [2,3]=binB count  [8,9]=s1(float) [10,11]=s2(float)
//   [14,15]=sums ticket  (rest pad; all zeroed by prep block 0)

// ---- fused prep: pad decode + zero | weight swizzle | MFMA projection chain
__global__ __launch_bounds__(256) void prep_kernel(
    const void* lp, const void* pp, unsigned char* lmask, unsigned char* pmask,
    const float* __restrict__ W1, const float* __restrict__ W2,
    unsigned short* __restrict__ W1xf, unsigned short* __restrict__ W2f,
    const float* __restrict__ l_tok, const float* __restrict__ p_tok,
    const float* __restrict__ Wl, const float* __restrict__ bl,
    const float* __restrict__ Wp, const float* __restrict__ bp,
    const float* __restrict__ b1,
    float* __restrict__ wl_, float* __restrict__ wp_,
    float* __restrict__ wA, float* __restrict__ wB,
    unsigned* __restrict__ zero_base) {
  __shared__ int bad;
  const int tid = threadIdx.x;
  if (blockIdx.x == 0) {
    for (int i = tid; i < NB * NBIN + 32; i += 256) zero_base[i] = 0u;
    if (tid == 0) bad = 0;
    __syncthreads();
    const unsigned int* li = (const unsigned int*)lp;
    const unsigned int* pi = (const unsigned int*)pp;
    for (int i = tid; i < NB * LL; i += 256) if (li[i] > 1u) atomicOr(&bad, 1);
    for (int i = tid; i < NB * LP; i += 256) if (pi[i] > 1u) atomicOr(&bad, 1);
    __syncthreads();
    const bool asInt = (bad == 0);
    const unsigned char* lb = (const unsigned char*)lp;
    const unsigned char* pb = (const unsigned char*)pp;
    for (int i = tid; i < NB * LL; i += 256)
      lmask[i] = asInt ? (unsigned char)(li[i] != 0u) : (unsigned char)(lb[i] != 0);
    for (int i = tid; i < NB * LP; i += 256)
      pmask[i] = asInt ? (unsigned char)(pi[i] != 0u) : (unsigned char)(pb[i] != 0);
    return;
  }
  if (blockIdx.x < 321) {
    int idx = (blockIdx.x - 1) * 256 + tid;
    if (idx < 65536) {
      int j = idx & 7, ln = (idx >> 3) & 63;
      int rest = idx >> 9;
      int mt = rest & 7, kt = (rest >> 3) & 1, cc = rest >> 4;
      int row = 512 + cc * 64 + kt * 32 + ((ln >> 4) << 3) + j;
      int col = mt * 16 + (ln & 15);
      W1xf[idx] = bfbits(W1[row * HD + col]);
    } else if (idx < 65536 + 16384) {
      int e = idx - 65536;
      int j = e & 7, ln = (e >> 3) & 63, mt = (e >> 9) & 7, kt = e >> 12;
      int row = kt * 32 + ((ln >> 4) << 3) + j;
      int col = mt * 16 + (ln & 15);
      W2f[e] = bfbits(W2[row * HD + col]);
    }
    return;
  }
  // ---- MFMA projection chain: Y1 = X@W+b; Y2 = Y1@W1part(+b1) ----
  const int pblk = blockIdx.x - 321;
  const bool isL = pblk < (NB * LL / 16);
  const int blk = isL ? pblk : (pblk - NB * LL / 16);
  const int r0 = blk * 16;
  const float* X = isL ? l_tok : p_tok;
  const float* W = isL ? Wl : Wp;
  const float* bias = isL ? bl : bp;
  float* Y1 = isL ? wl_ : wp_;
  float* Y2 = isL ? wA : wB;
  const float* W1p = isL ? W1 : (W1 + 256 * HD);

  const int lane = tid & 63;
  const int wv = tid >> 6;
  const int mrow = lane & 15;
  const int kg = (lane >> 4) * 8;
  const int drow = (lane >> 4) * 4;

  // phase A: 256 cols, wave wv owns nt = wv*4+q
  f32x4 accA[4];
#pragma unroll
  for (int q = 0; q < 4; ++q) {
    float bv = bias[(wv * 4 + q) * 16 + mrow];
    accA[q] = (f32x4){bv, bv, bv, bv};
  }
#pragma unroll
  for (int kt = 0; kt < 8; ++kt) {
    const float* xr = &X[(size_t)(r0 + mrow) * 256 + kt * 32 + kg];
    s16x8 af = pack8(*(const f32x4*)xr, *(const f32x4*)(xr + 4));
#pragma unroll
    for (int q = 0; q < 4; ++q) {
      const int nc = (wv * 4 + q) * 16 + mrow;
      f32x4 w0, w1;
#pragma unroll
      for (int j = 0; j < 4; ++j) {
        w0[j] = W[(size_t)(kt * 32 + kg + j) * 256 + nc];
        w1[j] = W[(size_t)(kt * 32 + kg + 4 + j) * 256 + nc];
      }
      accA[q] = mfma16(af, pack8(w0, w1), accA[q]);
    }
  }
#pragma unroll
  for (int q = 0; q < 4; ++q)
#pragma unroll
    for (int r = 0; r < 4; ++r)
      Y1[(size_t)(r0 + drow + r) * 256 + (wv * 4 + q) * 16 + mrow] = accA[q][r];
  __syncthreads();

  // phase B: 128 cols, wave wv owns nt = wv*2+q
  f32x4 accB[2];
#pragma unroll
  for (int q = 0; q < 2; ++q) {
    float bv = isL ? b1[(wv * 2 + q) * 16 + mrow] : 0.0f;
    accB[q] = (f32x4){bv, bv, bv, bv};
  }
#pragma unroll
  for (int kt = 0; kt < 8; ++kt) {
    const float* yr = &Y1[(size_t)(r0 + mrow) * 256 + kt * 32 + kg];
    s16x8 af = pack8(*(const f32x4*)yr, *(const f32x4*)(yr + 4));
#pragma unroll
    for (int q = 0; q < 2; ++q) {
      const int nc = (wv * 2 + q) * 16 + mrow;
      f32x4 w0, w1;
#pragma unroll
      for (int j = 0; j < 4; ++j) {
        w0[j] = W1p[(size_t)(kt * 32 + kg + j) * HD + nc];
        w1[j] = W1p[(size_t)(kt * 32 + kg + 4 + j) * HD + nc];
      }
      accB[q] = mfma16(af, pack8(w0, w1), accB[q]);
    }
  }
#pragma unroll
  for (int q = 0; q < 2; ++q)
#pragma unroll
    for (int r = 0; r < 4; ++r)
      Y2[(size_t)(r0 + drow + r) * HD + (wv * 2 + q) * 16 + mrow] = accB[q][r];
}

// ---- MFMA pair kernel: 8m x 2n, rcp-gelu, 3 blocks/CU + fused LDS hist -----
__global__ __launch_bounds__(256, 3) void pair2_kernel(
    const float* __restrict__ lbuf, const float* __restrict__ pbuf,
    const float* __restrict__ A1, const float* __restrict__ B1,
    const unsigned short* __restrict__ W1xf, const unsigned short* __restrict__ W2f,
    const float* __restrict__ b2, const float* __restrict__ W3,
    const float* __restrict__ b3, const unsigned char* __restrict__ lmask,
    const unsigned char* __restrict__ pmask, float* __restrict__ logits,
    unsigned* __restrict__ hist) {
  __shared__ float U[8192];

  const int tid = threadIdx.x;
  const int lane = tid & 63;
  const int w = tid >> 6;
  const int g = lane >> 4;
  const int c = lane & 15;
  const int bb = blockIdx.z;
  const int i0 = blockIdx.y * LB;
  const int j0 = blockIdx.x * PB;

  float* lt0 = U;
  float* lt1 = U + 1632;

  const int srow = tid >> 4, sq = tid & 15;
  const int srow2 = (tid + 256) >> 4;

  auto gaddr = [&](int row, int q, int c4) -> const float* {
    return (row < 8)
        ? &lbuf[(size_t)(bb * LL + i0 + row) * BD + c4 * 64 + q * 4]
        : &pbuf[(size_t)(bb * LP + j0 + (row - 8)) * BD + c4 * 64 + q * 4];
  };

  {
    f32x4 r0 = *(const f32x4*)gaddr(srow, sq, 0);
    f32x4 r1 = {};
    if (tid < 128) r1 = *(const f32x4*)gaddr(srow2, sq, 0);
    *(f32x4*)&lt0[srow * 68 + sq * 4] = r0;
    if (tid < 128) *(f32x4*)&lt0[srow2 * 68 + sq * 4] = r1;
  }
  __syncthreads();

  f32x4 acc1[8][2];
#pragma unroll
  for (int m = 0; m < 8; ++m)
#pragma unroll
    for (int n = 0; n < 2; ++n) acc1[m][n] = (f32x4)0.0f;

  for (int c4 = 0; c4 < 4; ++c4) {
    float* cur = (c4 & 1) ? lt1 : lt0;
    float* nxt = (c4 & 1) ? lt0 : lt1;

    f32x4 r0 = {}, r1 = {};
    if (c4 < 3) {
      r0 = *(const f32x4*)gaddr(srow, sq, c4 + 1);
      if (tid < 128) r1 = *(const f32x4*)gaddr(srow2, sq, c4 + 1);
    }

#pragma unroll
    for (int kt = 0; kt < 2; ++kt) {
      const int kc0 = kt * 32 + g * 8;
      // A-frag batch 0 in flight...
      s16x8 a0[8];
#pragma unroll
      for (int m = 0; m < 8; ++m)
        a0[m] = *(const s16x8*)(W1xf +
            ((size_t)((c4 * 2 + kt) * 8 + m) * 64 + lane) * 8);

      // ...covered by bf0 build
      const f32x4 p0 = *(const f32x4*)&cur[(8 + c) * 68 + kc0];
      const f32x4 p1 = *(const f32x4*)&cur[(8 + c) * 68 + kc0 + 4];
      s16x8 bf0[2], bf1[2];
#pragma unroll
      for (int n = 0; n < 2; ++n) {
        const int ntg = w * 2 + n;
        const f32x4 l0 = *(const f32x4*)&cur[ntg * 68 + kc0];
        const f32x4 l1 = *(const f32x4*)&cur[ntg * 68 + kc0 + 4];
        u32x4 bv;
        bv[0] = pack_bf16(l0[0] * p0[0], l0[1] * p0[1]);
        bv[1] = pack_bf16(l0[2] * p0[2], l0[3] * p0[3]);
        bv[2] = pack_bf16(l1[0] * p1[0], l1[1] * p1[1]);
        bv[3] = pack_bf16(l1[2] * p1[2], l1[3] * p1[3]);
        bf0[n] = as_s16x8(bv);
      }

      // A-frag batch 1 in flight...
      s16x8 a1[8];
#pragma unroll
      for (int m = 0; m < 8; ++m)
        a1[m] = *(const s16x8*)(W1xf +
            ((size_t)(((4 + c4) * 2 + kt) * 8 + m) * 64 + lane) * 8);

      // ...covered by bf1 build
#pragma unroll
      for (int n = 0; n < 2; ++n) {
        const int ntg = w * 2 + n;
        const f32x4 l0 = *(const f32x4*)&cur[ntg * 68 + kc0];
        const f32x4 l1 = *(const f32x4*)&cur[ntg * 68 + kc0 + 4];
        u32x4 bv;
        bv[0] = pack_bf16(fabsf(l0[0] - p0[0]), fabsf(l0[1] - p0[1]));
        bv[1] = pack_bf16(fabsf(l0[2] - p0[2]), fabsf(l0[3] - p0[3]));
        bv[2] = pack_bf16(fabsf(l1[0] - p1[0]), fabsf(l1[1] - p1[1]));
        bv[3] = pack_bf16(fabsf(l1[2] - p1[2]), fabsf(l1[3] - p1[3]));
        bf1[n] = as_s16x8(bv);
      }

#pragma unroll
      for (int m = 0; m < 8; ++m) {
        acc1[m][0] = mfma16(a0[m], bf0[0], acc1[m][0]);
        acc1[m][1] = mfma16(a0[m], bf0[1], acc1[m][1]);
      }
#pragma unroll
      for (int m = 0; m < 8; ++m) {
        acc1[m][0] = mfma16(a1[m], bf1[0], acc1[m][0]);
        acc1[m][1] = mfma16(a1[m], bf1[1], acc1[m][1]);
      }
    }

    if (c4 < 3) {
      *(f32x4*)&nxt[srow * 68 + sq * 4] = r0;
      if (tid < 128) *(f32x4*)&nxt[srow2 * 68 + sq * 4] = r1;
    }
    __syncthreads();
  }

  unsigned* Hdw = (unsigned*)U;
#pragma unroll
  for (int m = 0; m < 8; ++m) {
    const int kt2 = (4 * m + g) >> 3;
    const int l2 = ((2 * m + (g >> 1)) & 3) * 16 + c;
    const int jd = (g & 1) * 2;
    const f32x4 b1v = *(const f32x4*)&B1[(size_t)(bb * LP + j0 + c) * HD + m * 16 + g * 4];
#pragma unroll
    for (int n = 0; n < 2; ++n) {
      const int ntg = w * 2 + n;
      f32x4 a1v = *(const f32x4*)&A1[(size_t)(bb * LL + i0 + ntg) * HD + m * 16 + g * 4];
      float h0 = gelu_fast(acc1[m][n][0] + a1v[0] + b1v[0]);
      float h1 = gelu_fast(acc1[m][n][1] + a1v[1] + b1v[1]);
      float h2 = gelu_fast(acc1[m][n][2] + a1v[2] + b1v[2]);
      float h3 = gelu_fast(acc1[m][n][3] + a1v[3] + b1v[3]);
      uint2 hw;
      hw.x = pack_bf16(h0, h1);
      hw.y = pack_bf16(h2, h3);
      *(uint2*)&Hdw[((kt2 * 8 + ntg) * 64 + l2) * 4 + jd] = hw;
    }
  }
  __syncthreads();

  f32x4 acc2[8][2];
#pragma unroll
  for (int m = 0; m < 8; ++m)
#pragma unroll
    for (int n = 0; n < 2; ++n) acc2[m][n] = (f32x4)0.0f;

  const unsigned short* Hush = (const unsigned short*)U;
#pragma unroll
  for (int kt = 0; kt < 4; ++kt) {
    s16x8 a2[8];
#pragma unroll
    for (int m = 0; m < 8; ++m)
      a2[m] = *(const s16x8*)(W2f + (size_t)((kt * 8 + m) * 64 + lane) * 8);
    s16x8 bf[2];
#pragma unroll
    for (int n = 0; n < 2; ++n)
      bf[n] = *((const s16x8*)Hush + ((kt * 8 + (w * 2 + n)) * 64 + lane));
#pragma unroll
    for (int m = 0; m < 8; ++m) {
      acc2[m][0] = mfma16(a2[m], bf[0], acc2[m][0]);
      acc2[m][1] = mfma16(a2[m], bf[1], acc2[m][1]);
    }
  }

  float partial[2] = {0.0f, 0.0f};
#pragma unroll
  for (int m = 0; m < 8; ++m) {
    const int hb = m * 16 + g * 4;
    f32x4 b2v = *(const f32x4*)&b2[hb];
    f32x4 w3v = *(const f32x4*)&W3[hb];
#pragma unroll
    for (int n = 0; n < 2; ++n) {
#pragma unroll
      for (int r = 0; r < 4; ++r)
        partial[n] = fmaf(gelu_fast(acc2[m][n][r] + b2v[r]), w3v[r], partial[n]);
    }
  }
#pragma unroll
  for (int n = 0; n < 2; ++n) {
    partial[n] += __shfl_xor(partial[n], 16, 64);
    partial[n] += __shfl_xor(partial[n], 32, 64);
  }
  const bool writer = (g == 0);
  float vv0 = NEGV, vv1 = NEGV;
  if (writer) {
    const float bb3 = b3[0];
    {
      float v = partial[0] + bb3;
      if (isnan(v)) v = 0.0f;
      else if (isinf(v)) v = (v > 0.0f) ? 20.0f : NEGV;
      const int i = i0 + w * 2, j = j0 + c;
      if (lmask[bb * LL + i] || pmask[bb * LP + j]) v = NEGV;
      logits[(size_t)bb * NLOG + i * LP + j] = v;
      vv0 = v;
    }
    {
      float v = partial[1] + bb3;
      if (isnan(v)) v = 0.0f;
      else if (isinf(v)) v = (v > 0.0f) ? 20.0f : NEGV;
      const int i = i0 + w * 2 + 1, j = j0 + c;
      if (lmask[bb * LL + i] || pmask[bb * LP + j]) v = NEGV;
      logits[(size_t)bb * NLOG + i * LP + j] = v;
      vv1 = v;
    }
  }

  // ---- fused per-block LDS histogram of this block's 128 logits ----
  unsigned* lh = (unsigned*)U;
  __syncthreads();  // all Hush reads done -> U reusable
  for (int i = tid; i < NBIN; i += 256) lh[i] = 0u;
  __syncthreads();
  if (writer) {
    atomicAdd(&lh[fkey(vv0) >> BSHIFT], 1u);
    atomicAdd(&lh[fkey(vv1) >> BSHIFT], 1u);
  }
  __syncthreads();
  unsigned* gh = hist + bb * NBIN;
  for (int i = tid; i < NBIN; i += 256) {
    unsigned v = lh[i];
    if (v) atomicAdd(&gh[i], v);
  }
}

// ----- topk2: redundant findbin (hist complete at kernel boundary) ->
//       sums + candidate collect -> last-block exact select ------------------
__global__ __launch_bounds__(256) void topk2_kernel(const float* __restrict__ logits,
                                                    const unsigned* __restrict__ hist,
                                                    unsigned* __restrict__ ctrl,
                                                    float* __restrict__ cand,
                                                    float* __restrict__ out) {
  __shared__ unsigned csum[256];
  __shared__ unsigned suf[256];
  __shared__ unsigned topb[256];
  __shared__ float red[256];
  __shared__ unsigned sB, sG, sUB, sP, sN, isLastS;
  __shared__ unsigned bc[4];
  const int b = blockIdx.y;
  const int tid = threadIdx.x;
  const float* data = logits + (size_t)b * NLOG;
  const unsigned* gh = hist + b * NBIN;
  const int stride = gridDim.x * 256;

  // ---- per-block findbin (deterministic; hist is complete) ----
  const int base = tid * (NBIN / 256);
  {
    unsigned s = 0;
    int top = -1;
    for (int i = 0; i < NBIN / 256; ++i) {
      unsigned cnt = gh[base + i];
      s += cnt;
      if (cnt) top = base + i;
    }
    csum[tid] = s;
    topb[tid] = (unsigned)(top + 1);
  }
  __syncthreads();
  if (tid == 0) {
    unsigned a = 0;
    for (int t = 255; t >= 0; --t) { suf[t] = a; a += csum[t]; }
    unsigned mt = 0;
    for (int t = 0; t < 256; ++t) mt = max(mt, topb[t]);
    sUB = ((mt - 1u) << BSHIFT) | ((1u << BSHIFT) - 1u);  // ub >= true max
  }
  __syncthreads();
  {
    unsigned above = suf[tid];
    if (above < 100u && above + csum[tid] >= 100u) {
      unsigned a = above;
      for (int i = NBIN / 256 - 1; i >= 0; --i) {
        unsigned hc = gh[base + i];
        if (a + hc >= 100u) { sB = base + i; sG = a; break; }
        a += hc;
      }
    }
  }
  __syncthreads();
  const unsigned B = sB;
  const unsigned G = sG;
  const float vmax = finv(sUB);

  // ---- sums above bin B + collect bin-B candidates ----
  {
    float l1 = 0.0f, l2 = 0.0f;
    for (int i = blockIdx.x * 256 + tid; i < NLOG; i += stride) {
      float v = data[i];
      unsigned kb = fkey(v) >> BSHIFT;
      if (kb > B) {
        float e = __expf(v - vmax);
        l1 += e;
        l2 = fmaf(e, v, l2);
      } else if (kb == B) {
        unsigned pos = atomicAdd(&ctrl[2 + b], 1u);
        if (pos < CAP) cand[(size_t)b * CAP + pos] = v;
      }
    }
    if (l1 != 0.0f) {
      atomicAdd((float*)&ctrl[8 + b], l1);
      atomicAdd((float*)&ctrl[10 + b], l2);
    }
  }
  __threadfence();
  if (tid == 0) isLastS = (atomicAdd(&ctrl[14 + b], 1u) == gridDim.x - 1);
  __syncthreads();
  if (!isLastS) return;
  __threadfence();  // acquire: cand + partial sums visible

  // ---- final: exact select among candidates + combine ----
  if (tid == 0) {
    bc[0] = atomicAdd(&ctrl[2 + b], 0u);
    bc[1] = __float_as_uint(atomicAdd((float*)&ctrl[8 + b], 0.0f));
    bc[2] = __float_as_uint(atomicAdd((float*)&ctrl[10 + b], 0.0f));
  }
  __syncthreads();
  const unsigned count = bc[0];
  const float s1g = __uint_as_float(bc[1]);
  const float s2g = __uint_as_float(bc[2]);
  const float* cv = cand + (size_t)b * CAP;
  const bool fb = count > CAP;  // degenerate fallback: full-array select
  const unsigned C = fb ? 0u : count;

  if (tid == 0) { sP = 0u; sN = fb ? 100u : (100u - G); }
  __syncthreads();

  for (int sh = 24; sh >= 0; sh -= 8) {
    csum[tid] = 0u;
    __syncthreads();
    const unsigned prefix = sP;
    const unsigned maskhi = (sh == 24) ? 0u : (0xFFFFFFFFu << (sh + 8));
    if (!fb) {
      for (int i = tid; i < (int)C; i += 256) {
        unsigned k = fkey(cv[i]);
        if ((k & maskhi) == (prefix & maskhi)) atomicAdd(&csum[(k >> sh) & 255], 1u);
      }
    } else {
      for (int i = tid; i < NLOG; i += 256) {
        unsigned k = fkey(data[i]);
        if ((k & maskhi) == (prefix & maskhi)) atomicAdd(&csum[(k >> sh) & 255], 1u);
      }
    }
    __syncthreads();
    if (tid == 0) {
      unsigned need = sN, cum = 0u;
      int d = 0;
      for (d = 255; d >= 0; --d) { cum += csum[d]; if (cum >= need) break; }
      sN = need - (cum - csum[d]);
      sP = prefix | ((unsigned)d << sh);
    }
    __syncthreads();
  }
  const unsigned Tkey = sP;
  const unsigned nT = sN;
  const float T = finv(Tkey);

  float l1 = 0.0f, l2 = 0.0f;
  if (!fb) {
    for (int i = tid; i < (int)C; i += 256) {
      float v = cv[i];
      if (fkey(v) > Tkey) { float e = __expf(v - vmax); l1 += e; l2 = fmaf(e, v, l2); }
    }
  } else {
    for (int i = tid; i < NLOG; i += 256) {
      float v = data[i];
      if (fkey(v) > Tkey) { float e = __expf(v - vmax); l1 += e; l2 = fmaf(e, v, l2); }
    }
  }
  red[tid] = l1;
  __syncthreads();
  for (int s = 128; s > 0; s >>= 1) { if (tid < s) red[tid] += red[tid + s]; __syncthreads(); }
  const float s1c = red[0];
  __syncthreads();
  red[tid] = l2;
  __syncthreads();
  for (int s = 128; s > 0; s >>= 1) { if (tid < s) red[tid] += red[tid + s]; __syncthreads(); }
  if (tid == 0) {
    const float s2c = red[0];
    const float e = __expf(T - vmax);
    const float g1 = fb ? 0.0f : s1g;
    const float g2 = fb ? 0.0f : s2g;
    const float denom = g1 + s1c + (float)nT * e;
    const float num = g2 + s2c + (float)nT * e * T;
    out[b] = num / denom;
  }
}

// ---------------------------------------------------------------------------
extern "C" void kernel_launch(void* const* d_in, const int* in_sizes, int n_in,
                              void* d_out, int out_size, void* d_ws, size_t ws_size,
                              hipStream_t stream) {
  const float* l_tok = (const float*)d_in[0];
  const float* p_tok = (const float*)d_in[1];
  const void* l_pad = d_in[2];
  const void* p_pad = d_in[3];
  const float* Wl = (const float*)d_in[4];
  const float* bl = (const float*)d_in[5];
  const float* Wp = (const float*)d_in[6];
  const float* bp = (const float*)d_in[7];
  const float* W1 = (const float*)d_in[8];
  const float* b1 = (const float*)d_in[9];
  const float* W2 = (const float*)d_in[10];
  const float* b2 = (const float*)d_in[11];
  const float* W3 = (const float*)d_in[12];
  const float* b3 = (const float*)d_in[13];

  float* ws = (float*)d_ws;
  float* wl_ = ws;                    // Y1 ligand [2,96,256]
  float* wp_ = ws + 49152;            // Y1 protein [2,768,256]
  float* wA = ws + 442368;            // A1 [2,96,128]
  float* wB = ws + 466944;            // B1 [2,768,128]
  float* wLog = ws + 663552;          // logits [2,73728]
  unsigned char* lmask = (unsigned char*)(ws + 811008);
  unsigned char* pmask = lmask + NB * LL;
  unsigned short* W1xf = (unsigned short*)(ws + 811520);  // 65536 u16
  unsigned short* W2f = (unsigned short*)(ws + 844288);   // 16384 u16
  unsigned* hist = (unsigned*)(ws + 852480);              // [2][NBIN] u32
  unsigned* ctrl = (unsigned*)(ws + 852480 + NB * NBIN);  // 32 u32
  float* cand = ws + 852480 + NB * NBIN + 32;             // [2][CAP]

  prep_kernel<<<321 + NB * (LL + LP) / 16, 256, 0, stream>>>(
      l_pad, p_pad, lmask, pmask, W1, W2, W1xf, W2f,
      l_tok, p_tok, Wl, bl, Wp, bp, b1, wl_, wp_, wA, wB, hist);

  dim3 grid(LP / PB, LL / LB, NB);
  pair2_kernel<<<grid, 256, 0, stream>>>(wl_, wp_, wA, wB, W1xf, W2f,
                                         b2, W3, b3, lmask, pmask, wLog, hist);

  topk2_kernel<<<dim3(64, NB), 256, 0, stream>>>(wLog, hist, ctrl, cand,
                                                 (float*)d_out);
}